// Round 14
// baseline (304.982 us; speedup 1.0000x reference)
//
#include <hip/hip_runtime.h>
#include <math.h>

typedef unsigned int u32;
typedef unsigned short u16;
typedef u32 u32x4 __attribute__((ext_vector_type(4)));
typedef float f32x4 __attribute__((ext_vector_type(4)));
typedef float f32x2 __attribute__((ext_vector_type(2)));

#define RLN2 1.4426950408889634f

__device__ __forceinline__ u16 f2bf(float f) {
  u32 u = __builtin_bit_cast(u32, f);
  return (u16)((u + 0x7FFFu + ((u >> 16) & 1u)) >> 16);
}
__device__ __forceinline__ void mfma16(f32x4& c, const u32x4& a, const u32x4& b) {
  asm volatile("v_mfma_f32_16x16x32_bf16 %0, %1, %2, %0" : "+v"(c) : "v"(a), "v"(b));
}
// packed fp32 fma: acc = val*w + acc
__device__ __forceinline__ void pkfma(f32x2& acc, f32x2 val, f32x2 w) {
  asm volatile("v_pk_fma_f32 %0, %1, %2, %0" : "+v"(acc) : "v"(val), "v"(w));
}
__device__ __forceinline__ f32x2 unpk(u32 u) {
  f32x2 v;
  v.x = __builtin_bit_cast(float, u << 16);
  v.y = __builtin_bit_cast(float, u & 0xffff0000u);
  return v;
}
__device__ __forceinline__ float lrelu(float e) { return fmaxf(e, 0.2f * e); }

// ---------------------------------------------------------------------------
// PREP-1 (merged): blocks [0,256) = BN stats; blocks [256,..) = CSR count.
// ---------------------------------------------------------------------------
__global__ void prep1_kernel(const float* __restrict__ x, float* __restrict__ musum,
                             float* __restrict__ sqsum, const int* __restrict__ ei, int E,
                             int N, int* __restrict__ cnt) {
  int b = blockIdx.x;
  int t = threadIdx.x;
  if (b < 256) {
    float s = 0.f, s2 = 0.f;
    for (int r = b; r < N; r += 256) {
      float v = x[(size_t)r * 256 + t];
      s += v;
      s2 += v * v;
    }
    atomicAdd(&musum[t], s);
    atomicAdd(&sqsum[t], s2);
  } else {
    int e = (b - 256) * 256 + t;
    int ET = E + N;
    if (e < ET) {
      int d = (e < E) ? ei[E + e] : (e - E);
      atomicAdd(&cnt[d], 1);
    }
  }
}

// ---------------------------------------------------------------------------
// PREP-2 (merged, 1024 threads): block 0 = scan + perm; blocks 1.. = BN apply
// ---------------------------------------------------------------------------
__global__ __launch_bounds__(1024) void prep2_kernel(
    int* __restrict__ cnt, int* __restrict__ row_ptr, int* __restrict__ perm,
    const float* __restrict__ x, const float* __restrict__ musum,
    const float* __restrict__ sqsum, const float* __restrict__ gamma,
    const float* __restrict__ beta, u16* __restrict__ xin, int N, float invN) {
  int t = threadIdx.x;
  if (blockIdx.x == 0) {
    __shared__ int part[1024];
    __shared__ int bins[256];
    __shared__ int bs[256];
    int chunk = (N + 1023) / 1024;
    int lo = min(t * chunk, N);
    int hi = min(lo + chunk, N);
    if (t < 256) bins[t] = 0;
    __syncthreads();
    int s = 0;
    for (int i = lo; i < hi; i++) {
      int d = cnt[i];
      s += d;
      atomicAdd(&bins[min(d, 255)], 1);
    }
    part[t] = s;
    __syncthreads();
    for (int off = 1; off < 1024; off <<= 1) {
      int v = (t >= off) ? part[t - off] : 0;
      __syncthreads();
      part[t] += v;
      __syncthreads();
    }
    if (t < 256) bs[t] = bins[t];
    __syncthreads();
    for (int off = 1; off < 256; off <<= 1) {
      int v = (t < 256 && t >= off) ? bs[t - off] : 0;
      __syncthreads();
      if (t < 256) bs[t] += v;
      __syncthreads();
    }
    if (t < 256) bins[t] = (t == 0) ? 0 : bs[t - 1];
    __syncthreads();
    for (int i = lo; i < hi; i++) {
      int d = min(cnt[i], 255);
      int pos = atomicAdd(&bins[d], 1);
      perm[pos] = i;
    }
    __syncthreads();
    int run = (t == 0) ? 0 : part[t - 1];
    for (int i = lo; i < hi; i++) {
      int d = cnt[i];
      row_ptr[i] = run;
      cnt[i] = run;
      run += d;
    }
    if (t == 1023) row_ptr[N] = part[1023];
  } else {
    int col = t & 255, ro = t >> 8;
    float mu = musum[col] * invN;
    float var = sqsum[col] * invN - mu * mu;
    float sc = gamma[col] * rsqrtf(var + 1e-5f);
    float sh = beta[col] - mu * sc;
    for (int r = (blockIdx.x - 1) * 4 + ro; r < N; r += 256 * 4) {
      size_t idx = (size_t)r * 256 + col;
      xin[idx] = f2bf(x[idx] * sc + sh);
    }
  }
}

// ---------------------------------------------------------------------------
// PREP-3 (merged): CSR fill || weight prep. al-fold rows are pre-scaled by
// RLN2 so aggregation can use exp2 (base-2 softmax; exp2(x/ln2)==exp(x)).
// ---------------------------------------------------------------------------
__global__ void prep3_kernel(const int* __restrict__ ei, int E, int N, int FILLB,
                             int* __restrict__ cursor, int* __restrict__ csr_src,
                             const float* __restrict__ W1, const float* __restrict__ a1s,
                             const float* __restrict__ a1d, const float* __restrict__ W2,
                             const float* __restrict__ a2s, const float* __restrict__ a2d,
                             const float* __restrict__ W3, const float* __restrict__ a3s,
                             const float* __restrict__ a3d, u16* __restrict__ Wt1,
                             u16* __restrict__ Wt2, u16* __restrict__ Wt3) {
  int b = blockIdx.x;
  if (b < FILLB) {
    int e = b * 256 + threadIdx.x;
    int ET = E + N;
    if (e < ET) {
      int s, d;
      if (e < E) { s = ei[e]; d = ei[E + e]; }
      else       { s = e - E; d = s; }
      int pos = atomicAdd(&cursor[d], 1);
      csr_src[pos] = s;
    }
    return;
  }
  const int S1 = 1024 * 256, S2 = 64 * 1280, S3 = 128 * 64;
  const int A1 = 32 * 256, A2 = 16 * 1280, A3 = 16 * 64;
  const int Z1 = 96 * 256, Z2 = 16 * 1280, Z3 = 16 * 64;
  int o = (b - FILLB) * 256 + threadIdx.x;
  if (o < S1) {
    int n = o / 256, k = o % 256;
    Wt1[o] = f2bf(W1[(size_t)k * 1024 + n]);
    return;
  }
  o -= S1;
  if (o < S2) {
    int n = o / 1280, k = o % 1280;
    Wt2[o] = f2bf(W2[(size_t)k * 64 + n]);
    return;
  }
  o -= S2;
  if (o < S3) {
    int n = o / 64, k = o % 64;
    Wt3[o] = f2bf(W3[(size_t)k * 128 + n]);
    return;
  }
  o -= S3;
  if (o < A1) {
    int jj = o / 256, k = o % 256, h = jj >> 1;
    const float* av = (jj & 1) ? a1d : a1s;
    float s = 0.f;
    for (int c = 0; c < 64; c++) s += W1[(size_t)k * 1024 + h * 64 + c] * av[h * 64 + c];
    Wt1[(size_t)(1024 + jj) * 256 + k] = f2bf(s * RLN2);
    return;
  }
  o -= A1;
  if (o < A2) {
    int jj = o / 1280, k = o % 1280, h = jj >> 1;
    const float* av = (jj & 1) ? a2d : a2s;
    float s = 0.f;
    for (int c = 0; c < 8; c++) s += W2[(size_t)k * 64 + h * 8 + c] * av[h * 8 + c];
    Wt2[(size_t)(64 + jj) * 1280 + k] = f2bf(s * RLN2);
    return;
  }
  o -= A2;
  if (o < A3) {
    int jj = o / 64, k = o % 64, h = jj >> 1;
    const float* av = (jj & 1) ? a3d : a3s;
    float s = 0.f;
    for (int c = 0; c < 16; c++) s += W3[(size_t)k * 128 + h * 16 + c] * av[h * 16 + c];
    Wt3[(size_t)(128 + jj) * 64 + k] = f2bf(s * RLN2);
    return;
  }
  o -= A3;
  if (o < Z1) { Wt1[1056 * 256 + o] = 0; return; }
  o -= Z1;
  if (o < Z2) { Wt2[80 * 1280 + o] = 0; return; }
  o -= Z2;
  if (o < Z3) { Wt3[144 * 64 + o] = 0; return; }
}

// ---------------------------------------------------------------------------
// bf16 MFMA GEMM, generalized BK, double-buffered LDS via global_load_lds.
// Fused al epilogue (transposed [H][ALP] al output, base-2-scaled logits).
// ---------------------------------------------------------------------------
template <int BM, int BN, int FM, int FN, int BK>
__global__ __launch_bounds__(256) void mfma_gemm_al(
    const u16* __restrict__ A1, const u16* __restrict__ A2, int K1, int K,
    const u16* __restrict__ Wt, u16* __restrict__ Ch, int NcH,
    float* __restrict__ als, float* __restrict__ ald, int ALN, int ALP, int M) {
  constexpr int KC8 = BK / 8;
  constexpr int ACH = (BM * BK) / 8;
  constexpr int BCH = (BN * BK) / 8;
  static_assert(BM == 2 * FM * 16 && BN == 2 * FN * 16, "wave grid 2x2");
  __shared__ u16 As[2][BM * BK];
  __shared__ u16 Bs[2][BN * BK];
  int t = threadIdx.x;
  int m0 = blockIdx.x * BM, n0 = blockIdx.y * BN;
  int r = t & 15;
  int g = (t >> 4) & 3;
  int wid = t >> 6;
  int wm0 = (wid >> 1) * (FM * 16);
  int wn0 = (wid & 1) * (FN * 16);
  int K8 = K >> 3;
  int K2 = K - K1;

  auto stage = [&](int buf, int k0) {
    const u16* Aseg;
    int sA, kl;
    if (k0 < K1) { Aseg = A1; sA = K1; kl = k0; }
    else         { Aseg = A2; sA = K2; kl = k0 - K1; }
#pragma unroll
    for (int i = 0; i < (ACH + 255) / 256; i++) {
      int c = i * 256 + t;
      if (ACH % 256 == 0 || c < ACH) {
        int m = c / KC8, kb = c % KC8;
        __builtin_amdgcn_global_load_lds(
            (const __attribute__((address_space(1))) void*)(Aseg + (size_t)(m0 + m) * sA + kl + kb * 8),
            (__attribute__((address_space(3))) void*)(&As[buf][c * 8]), 16, 0, 0);
      }
    }
#pragma unroll
    for (int i = 0; i < (BCH + 255) / 256; i++) {
      int c = i * 256 + t;
      if (BCH % 256 == 0 || c < BCH) {
        int nn = c / KC8, kb = c % KC8;
        __builtin_amdgcn_global_load_lds(
            (const __attribute__((address_space(1))) void*)(Wt + ((size_t)(n0 + nn) * K8 + (k0 >> 3) + kb) * 8),
            (__attribute__((address_space(3))) void*)(&Bs[buf][c * 8]), 16, 0, 0);
      }
    }
  };

  f32x4 acc[FM][FN] = {};
  asm volatile("s_nop 7\n\ts_nop 7" :::);  // VALU acc-init -> MFMA SrcC hazard guard

  stage(0, 0);
  __syncthreads();
  int nt = K / BK;
  for (int ts = 0; ts < nt; ts++) {
    if (ts + 1 < nt) stage((ts + 1) & 1, (ts + 1) * BK);
    int cur = ts & 1;
#pragma unroll
    for (int ks = 0; ks < BK / 32; ks++) {
      u32x4 af[FM], bfr[FN];
#pragma unroll
      for (int fi = 0; fi < FM; fi++)
        af[fi] = *(const u32x4*)(&As[cur][((wm0 + fi * 16 + r) * KC8 + ks * 4 + g) * 8]);
#pragma unroll
      for (int fj = 0; fj < FN; fj++)
        bfr[fj] = *(const u32x4*)(&Bs[cur][((wn0 + fj * 16 + r) * KC8 + ks * 4 + g) * 8]);
#pragma unroll
      for (int fi = 0; fi < FM; fi++)
#pragma unroll
        for (int fj = 0; fj < FN; fj++) mfma16(acc[fi][fj], af[fi], bfr[fj]);
    }
    __syncthreads();
  }
  asm volatile("s_nop 7\n\ts_nop 7" :::);  // MFMA -> VALU read hazard guard

#pragma unroll
  for (int fi = 0; fi < FM; fi++) {
#pragma unroll
    for (int fj = 0; fj < FN; fj++) {
#pragma unroll
      for (int v = 0; v < 4; v++) {
        int m = m0 + wm0 + fi * 16 + g * 4 + v;
        int nn = n0 + wn0 + fj * 16 + r;
        if (m < M) {
          float val = acc[fi][fj][v];
          if (nn < NcH) {
            Ch[(size_t)m * NcH + nn] = f2bf(val);
          } else {
            int j = nn - NcH;
            if (j < ALN) ((j & 1) ? ald : als)[(size_t)(j >> 1) * ALP + m] = val;
          }
        }
      }
    }
  }
}

// ---------------------------------------------------------------------------
// Layer-1 aggregation: GROUP-SLICED + XCD-affine + one-pass online base-2
// softmax (logits pre-scaled by 1/ln2). pk_fma inner loop.
// ---------------------------------------------------------------------------
__global__ __launch_bounds__(256) void gat_agg1_gs(
    const u16* __restrict__ xwh, const float* __restrict__ alsrc,
    const float* __restrict__ aldst, const int* __restrict__ row_ptr,
    const int* __restrict__ csr_src, const int* __restrict__ perm,
    const float* __restrict__ bias, const float* __restrict__ slope_p,
    u16* __restrict__ out, int N, int ALP, int NBH) {
  constexpr int U = 4;
  int b = blockIdx.x;
  int xcd = b & 7, seq = b >> 3;
  int phase = seq / NBH, nb = seq - phase * NBH;
  int h = xcd + (phase << 3);
  int lane = threadIdx.x & 63;
  int g = lane >> 3, l8 = lane & 7;
  int ti = nb * 32 + (threadIdx.x >> 6) * 8 + g;
  int n = perm[min(ti, N - 1)];
  const float* alh = alsrc + (size_t)h * ALP;
  float ad = aldst[(size_t)h * ALP + n];
  int start = row_ptr[n];
  int end = row_ptr[n + 1];
  int deg = (ti < N) ? end - start : 0;
  int endm1 = end - 1;

  float m = -1e30f, s = 0.f;
  f32x2 acc2[4] = {};
  const u16* base = xwh + (size_t)h * 64 + (size_t)l8 * 8;

  auto fma8 = [&](const u32x4& v, float w) {
    f32x2 w2;
    w2.x = w;
    w2.y = w;
#pragma unroll
    for (int i = 0; i < 4; i++) pkfma(acc2[i], unpk(v[i]), w2);
  };

  int c[U];
#pragma unroll
  for (int i = 0; i < U; i++) c[i] = csr_src[min(start + i, endm1)];
  int j = 0;
  for (; j + U <= deg; j += U) {
    u32x4 v[U];
    float e[U];
#pragma unroll
    for (int i = 0; i < U; i++) v[i] = *(const u32x4*)(base + (size_t)c[i] * 1024);
#pragma unroll
    for (int i = 0; i < U; i++) e[i] = lrelu(alh[c[i]] + ad);
#pragma unroll
    for (int i = 0; i < U; i++) c[i] = csr_src[min(start + j + U + i, endm1)];
    float mn = fmaxf(fmaxf(e[0], e[1]), fmaxf(e[2], e[3]));
    if (mn > m) {
      float sc = exp2f(m - mn);
      s *= sc;
#pragma unroll
      for (int k = 0; k < 4; k++) acc2[k] *= sc;
      m = mn;
    }
#pragma unroll
    for (int i = 0; i < U; i++) {
      float w = exp2f(e[i] - m);
      s += w;
      fma8(v[i], w);
    }
  }
  for (int i = 0; j < deg; j++, i++) {
    u32x4 v = *(const u32x4*)(base + (size_t)c[i] * 1024);
    float e = lrelu(alh[c[i]] + ad);
    if (e > m) {
      float sc = exp2f(m - e);
      s *= sc;
#pragma unroll
      for (int k = 0; k < 4; k++) acc2[k] *= sc;
      m = e;
    }
    float w = exp2f(e - m);
    s += w;
    fma8(v, w);
  }
  float rr = 1.f / (s + 1e-16f);

  if (ti < N) {
    float p = slope_p[0];
    u32 ow[4];
#pragma unroll
    for (int i = 0; i < 4; i++) {
      int cc = h * 64 + l8 * 8 + 2 * i;
      float v0 = acc2[i].x * rr + bias[cc];
      float v1 = acc2[i].y * rr + bias[cc + 1];
      v0 = (v0 >= 0.f) ? v0 : p * v0;
      v1 = (v1 >= 0.f) ? v1 : p * v1;
      ow[i] = (u32)f2bf(v0) | ((u32)f2bf(v1) << 16);
    }
    *(u32x4*)(out + (size_t)n * 1024 + h * 64 + l8 * 8) = *(u32x4*)ow;
  }
}

// ---------------------------------------------------------------------------
// Layer-2 aggregation: wave = 8 degree-matched nodes, base-2 online softmax.
// ---------------------------------------------------------------------------
__global__ __launch_bounds__(256) void gat_agg2_gs(
    const u16* __restrict__ xwh, const float* __restrict__ alsrc,
    const float* __restrict__ aldst, const int* __restrict__ row_ptr,
    const int* __restrict__ csr_src, const int* __restrict__ perm,
    const float* __restrict__ bias, const float* __restrict__ slope_p,
    u16* __restrict__ out, int N, int ALP) {
  constexpr int U = 4;
  int lane = threadIdx.x & 63;
  int g = lane >> 3, l8 = lane & 7;
  int ti = blockIdx.x * 32 + (threadIdx.x >> 6) * 8 + g;
  int n = perm[min(ti, N - 1)];
  const float* alh = alsrc + (size_t)l8 * ALP;
  float ad = aldst[(size_t)l8 * ALP + n];
  int start = row_ptr[n];
  int end = row_ptr[n + 1];
  int deg = (ti < N) ? end - start : 0;
  int endm1 = end - 1;

  float m = -1e30f, s = 0.f;
  f32x2 acc2[4] = {};
  const u16* base = xwh + (size_t)l8 * 8;

  auto fma8 = [&](const u32x4& v, float w) {
    f32x2 w2;
    w2.x = w;
    w2.y = w;
#pragma unroll
    for (int i = 0; i < 4; i++) pkfma(acc2[i], unpk(v[i]), w2);
  };

  int c[U];
#pragma unroll
  for (int i = 0; i < U; i++) c[i] = csr_src[min(start + i, endm1)];
  int j = 0;
  for (; j + U <= deg; j += U) {
    u32x4 v[U];
    float e[U];
#pragma unroll
    for (int i = 0; i < U; i++) v[i] = *(const u32x4*)(base + (size_t)c[i] * 64);
#pragma unroll
    for (int i = 0; i < U; i++) e[i] = lrelu(alh[c[i]] + ad);
#pragma unroll
    for (int i = 0; i < U; i++) c[i] = csr_src[min(start + j + U + i, endm1)];
    float mn = fmaxf(fmaxf(e[0], e[1]), fmaxf(e[2], e[3]));
    if (mn > m) {
      float sc = exp2f(m - mn);
      s *= sc;
#pragma unroll
      for (int k = 0; k < 4; k++) acc2[k] *= sc;
      m = mn;
    }
#pragma unroll
    for (int i = 0; i < U; i++) {
      float w = exp2f(e[i] - m);
      s += w;
      fma8(v[i], w);
    }
  }
  for (int i = 0; j < deg; j++, i++) {
    u32x4 v = *(const u32x4*)(base + (size_t)c[i] * 64);
    float e = lrelu(alh[c[i]] + ad);
    if (e > m) {
      float sc = exp2f(m - e);
      s *= sc;
#pragma unroll
      for (int k = 0; k < 4; k++) acc2[k] *= sc;
      m = e;
    }
    float w = exp2f(e - m);
    s += w;
    fma8(v, w);
  }
  float rr = 1.f / (s + 1e-16f);

  if (ti < N) {
    float p = slope_p[0];
    u32 ow[4];
#pragma unroll
    for (int i = 0; i < 4; i++) {
      int cc = l8 * 8 + 2 * i;
      float v0 = acc2[i].x * rr + bias[cc];
      float v1 = acc2[i].y * rr + bias[cc + 1];
      v0 = (v0 >= 0.f) ? v0 : p * v0;
      v1 = (v1 >= 0.f) ? v1 : p * v1;
      ow[i] = (u32)f2bf(v0) | ((u32)f2bf(v1) << 16);
    }
    *(u32x4*)(out + (size_t)n * 64 + l8 * 8) = *(u32x4*)ow;
  }
}

// ---------------------------------------------------------------------------
// Layer-3 aggregation: wave = 4 nodes x 16 lanes, base-2 online softmax,
// head-mean via shfl_xor, pairwise log_softmax.
// ---------------------------------------------------------------------------
__global__ __launch_bounds__(256) void gat_agg3_gs(
    const u16* __restrict__ xwh, const float* __restrict__ alsrc,
    const float* __restrict__ aldst, const int* __restrict__ row_ptr,
    const int* __restrict__ csr_src, const int* __restrict__ perm,
    const float* __restrict__ bias, float* __restrict__ out, int N, int ALP) {
  constexpr int U = 4;
  int lane = threadIdx.x & 63;
  int g = lane >> 4, l16 = lane & 15;
  int head = l16 >> 1;
  int ti = blockIdx.x * 16 + (threadIdx.x >> 6) * 4 + g;
  int n = perm[min(ti, N - 1)];
  const float* alh = alsrc + (size_t)head * ALP;
  float ad = aldst[(size_t)head * ALP + n];
  int start = row_ptr[n];
  int end = row_ptr[n + 1];
  int deg = (ti < N) ? end - start : 0;
  int endm1 = end - 1;

  float m = -1e30f, s = 0.f;
  f32x2 acc2[4] = {};
  const u16* base = xwh + (size_t)l16 * 8;

  auto fma8 = [&](const u32x4& v, float w) {
    f32x2 w2;
    w2.x = w;
    w2.y = w;
#pragma unroll
    for (int i = 0; i < 4; i++) pkfma(acc2[i], unpk(v[i]), w2);
  };

  int c[U];
#pragma unroll
  for (int i = 0; i < U; i++) c[i] = csr_src[min(start + i, endm1)];
  int j = 0;
  for (; j + U <= deg; j += U) {
    u32x4 v[U];
    float e[U];
#pragma unroll
    for (int i = 0; i < U; i++) v[i] = *(const u32x4*)(base + (size_t)c[i] * 128);
#pragma unroll
    for (int i = 0; i < U; i++) e[i] = lrelu(alh[c[i]] + ad);
#pragma unroll
    for (int i = 0; i < U; i++) c[i] = csr_src[min(start + j + U + i, endm1)];
    float mn = fmaxf(fmaxf(e[0], e[1]), fmaxf(e[2], e[3]));
    if (mn > m) {
      float sc = exp2f(m - mn);
      s *= sc;
#pragma unroll
      for (int k = 0; k < 4; k++) acc2[k] *= sc;
      m = mn;
    }
#pragma unroll
    for (int i = 0; i < U; i++) {
      float w = exp2f(e[i] - m);
      s += w;
      fma8(v[i], w);
    }
  }
  for (int i = 0; j < deg; j++, i++) {
    u32x4 v = *(const u32x4*)(base + (size_t)c[i] * 128);
    float e = lrelu(alh[c[i]] + ad);
    if (e > m) {
      float sc = exp2f(m - e);
      s *= sc;
#pragma unroll
      for (int k = 0; k < 4; k++) acc2[k] *= sc;
      m = e;
    }
    float w = exp2f(e - m);
    s += w;
    fma8(v, w);
  }
  float rr = 1.f / (s + 1e-16f);

  float a8[8];
#pragma unroll
  for (int k = 0; k < 4; k++) {
    a8[2 * k] = acc2[k].x * rr;
    a8[2 * k + 1] = acc2[k].y * rr;
  }

#pragma unroll
  for (int st = 2; st <= 8; st <<= 1)
#pragma unroll
    for (int k = 0; k < 8; k++) a8[k] += __shfl_xor(a8[k], st);

  int half = l16 & 1;
  float v8[8];
  float mx = -1e30f;
#pragma unroll
  for (int k = 0; k < 8; k++) {
    v8[k] = a8[k] * 0.125f + bias[half * 8 + k];
    mx = fmaxf(mx, v8[k]);
  }
  mx = fmaxf(mx, __shfl_xor(mx, 1));
  float se = 0.f;
#pragma unroll
  for (int k = 0; k < 8; k++) se += __expf(v8[k] - mx);
  se += __shfl_xor(se, 1);
  float lse = mx + logf(se);
  if (ti < N && l16 < 2) {
    float4 o0 = make_float4(v8[0] - lse, v8[1] - lse, v8[2] - lse, v8[3] - lse);
    float4 o1 = make_float4(v8[4] - lse, v8[5] - lse, v8[6] - lse, v8[7] - lse);
    float* op = out + (size_t)n * 16 + half * 8;
    *(float4*)op = o0;
    *(float4*)(op + 4) = o1;
  }
}

// ---------------------------------------------------------------------------
extern "C" void kernel_launch(void* const* d_in, const int* in_sizes, int n_in,
                              void* d_out, int out_size, void* d_ws, size_t ws_size,
                              hipStream_t stream) {
  const float* x        = (const float*)d_in[0];
  const int*   ei       = (const int*)d_in[1];
  const float* bn_gamma = (const float*)d_in[2];
  const float* bn_beta  = (const float*)d_in[3];
  const float* W1       = (const float*)d_in[4];
  const float* a1s      = (const float*)d_in[5];
  const float* a1d      = (const float*)d_in[6];
  const float* b1       = (const float*)d_in[7];
  const float* p1       = (const float*)d_in[8];
  const float* W2       = (const float*)d_in[9];
  const float* a2s      = (const float*)d_in[10];
  const float* a2d      = (const float*)d_in[11];
  const float* b2       = (const float*)d_in[12];
  const float* p2       = (const float*)d_in[13];
  const float* W3       = (const float*)d_in[14];
  const float* a3s      = (const float*)d_in[15];
  const float* a3d      = (const float*)d_in[16];
  const float* b3       = (const float*)d_in[17];
  float* out = (float*)d_out;

  const int F  = in_sizes[2];       // 256
  const int N  = in_sizes[0] / F;   // 20000
  const int E  = in_sizes[1] / 2;   // 320000
  const int ET = E + N;
  const int MP = ((N + 127) / 128) * 128;

  size_t off = 0;
  auto alloc = [&](size_t bytes) -> char* {
    char* r = (char*)d_ws + off;
    off += (bytes + 255) & ~(size_t)255;
    return r;
  };
  float* musum   = (float*)alloc(F * 4);
  float* sqsum   = (float*)alloc(F * 4);
  int*   cursor  = (int*)alloc((size_t)N * 4);
  int*   row_ptr = (int*)alloc((size_t)(N + 1) * 4);
  int*   csr_src = (int*)alloc((size_t)ET * 4);
  int*   perm    = (int*)alloc((size_t)N * 4);
  float* al_s    = (float*)alloc((size_t)16 * MP * 4);
  float* al_d    = (float*)alloc((size_t)16 * MP * 4);
  u16*   Wt1     = (u16*)alloc((size_t)1152 * 256 * 2);
  u16*   Wt2     = (u16*)alloc((size_t)96 * 1280 * 2);
  u16*   Wt3     = (u16*)alloc((size_t)160 * 64 * 2);
  u16*   x_in_h  = (u16*)alloc((size_t)MP * 256 * 2);
  u16*   xw1h    = (u16*)alloc((size_t)MP * 1024 * 2);
  u16*   h1      = (u16*)alloc((size_t)MP * 1024 * 2);
  u16*   xw2h    = (u16*)alloc((size_t)MP * 64 * 2);
  u16*   h2h     = (u16*)alloc((size_t)MP * 64 * 2);
  u16*   xw3h    = (u16*)alloc((size_t)MP * 128 * 2);

  hipMemsetAsync(musum, 0, (size_t)2 * F * 4 + (size_t)N * 4, stream);

  int CNTB = (ET + 255) / 256;
  prep1_kernel<<<256 + CNTB, 256, 0, stream>>>(x, musum, sqsum, ei, E, N, cursor);

  prep2_kernel<<<257, 1024, 0, stream>>>(cursor, row_ptr, perm, x, musum, sqsum, bn_gamma,
                                         bn_beta, x_in_h, N, 1.0f / (float)N);

  {
    int total_wt = 1024 * 256 + 64 * 1280 + 128 * 64
                 + 32 * 256 + 16 * 1280 + 16 * 64
                 + 96 * 256 + 16 * 1280 + 16 * 64;
    int WTB = (total_wt + 255) / 256;
    prep3_kernel<<<CNTB + WTB, 256, 0, stream>>>(ei, E, N, CNTB, cursor, csr_src, W1, a1s, a1d,
                                                 W2, a2s, a2d, W3, a3s, a3d, Wt1, Wt2, Wt3);
  }

  // ---- Layer 1 ----
  {
    dim3 grid(MP / 128, 9);
    mfma_gemm_al<128, 128, 4, 4, 32><<<grid, 256, 0, stream>>>(
        x_in_h, x_in_h, 256, 256, Wt1, xw1h, 1024, al_s, al_d, 32, MP, N);
    int NBH = (N + 31) / 32;
    gat_agg1_gs<<<8 * NBH * 2, 256, 0, stream>>>(xw1h, al_s, al_d, row_ptr, csr_src, perm, b1, p1,
                                                 h1, N, MP, NBH);
  }

  // ---- Layer 2 ----
  {
    dim3 grid((N + 31) / 32, 1);
    mfma_gemm_al<32, 96, 1, 3, 64><<<grid, 256, 0, stream>>>(
        x_in_h, h1, 256, 1280, Wt2, xw2h, 64, al_s, al_d, 16, MP, N);
    gat_agg2_gs<<<(N + 31) / 32, 256, 0, stream>>>(xw2h, al_s, al_d, row_ptr, csr_src, perm, b2,
                                                   p2, h2h, N, MP);
  }

  // ---- Layer 3 ----
  {
    dim3 grid((N + 63) / 64, 1);
    mfma_gemm_al<64, 160, 2, 5, 64><<<grid, 256, 0, stream>>>(
        h2h, h2h, 64, 64, Wt3, xw3h, 128, al_s, al_d, 16, MP, N);
    gat_agg3_gs<<<(N + 15) / 16, 256, 0, stream>>>(xw3h, al_s, al_d, row_ptr, csr_src, perm, b3,
                                                   out, N, MP);
  }
}

// Round 15
// 303.817 us; speedup vs baseline: 1.0038x; 1.0038x over previous
//
#include <hip/hip_runtime.h>
#include <math.h>

typedef unsigned int u32;
typedef unsigned short u16;
typedef u32 u32x4 __attribute__((ext_vector_type(4)));
typedef float f32x4 __attribute__((ext_vector_type(4)));
typedef float f32x2 __attribute__((ext_vector_type(2)));

__device__ __forceinline__ u16 f2bf(float f) {
  u32 u = __builtin_bit_cast(u32, f);
  return (u16)((u + 0x7FFFu + ((u >> 16) & 1u)) >> 16);
}
__device__ __forceinline__ void mfma16(f32x4& c, const u32x4& a, const u32x4& b) {
  asm volatile("v_mfma_f32_16x16x32_bf16 %0, %1, %2, %0" : "+v"(c) : "v"(a), "v"(b));
}
// packed fp32 fma: acc = val*w + acc (2 lanes worth per instruction)
__device__ __forceinline__ void pkfma(f32x2& acc, f32x2 val, f32x2 w) {
  asm volatile("v_pk_fma_f32 %0, %1, %2, %0" : "+v"(acc) : "v"(val), "v"(w));
}
// unpack u32 of 2 bf16 -> float2 {lo, hi}
__device__ __forceinline__ f32x2 unpk(u32 u) {
  f32x2 v;
  v.x = __builtin_bit_cast(float, u << 16);
  v.y = __builtin_bit_cast(float, u & 0xffff0000u);
  return v;
}
__device__ __forceinline__ float lrelu(float e) { return fmaxf(e, 0.2f * e); }

// ---------------------------------------------------------------------------
// PREP-1 (merged): blocks [0,256) = BN stats; blocks [256,..) = CSR count.
// ---------------------------------------------------------------------------
__global__ void prep1_kernel(const float* __restrict__ x, float* __restrict__ musum,
                             float* __restrict__ sqsum, const int* __restrict__ ei, int E,
                             int N, int* __restrict__ cnt) {
  int b = blockIdx.x;
  int t = threadIdx.x;
  if (b < 256) {
    float s = 0.f, s2 = 0.f;
    for (int r = b; r < N; r += 256) {
      float v = x[(size_t)r * 256 + t];
      s += v;
      s2 += v * v;
    }
    atomicAdd(&musum[t], s);
    atomicAdd(&sqsum[t], s2);
  } else {
    int e = (b - 256) * 256 + t;
    int ET = E + N;
    if (e < ET) {
      int d = (e < E) ? ei[E + e] : (e - E);
      atomicAdd(&cnt[d], 1);
    }
  }
}

// ---------------------------------------------------------------------------
// PREP-2 (merged, 1024 threads): block 0 = scan + perm; blocks 1.. = BN apply
// ---------------------------------------------------------------------------
__global__ __launch_bounds__(1024) void prep2_kernel(
    int* __restrict__ cnt, int* __restrict__ row_ptr, int* __restrict__ perm,
    const float* __restrict__ x, const float* __restrict__ musum,
    const float* __restrict__ sqsum, const float* __restrict__ gamma,
    const float* __restrict__ beta, u16* __restrict__ xin, int N, float invN) {
  int t = threadIdx.x;
  if (blockIdx.x == 0) {
    __shared__ int part[1024];
    __shared__ int bins[256];
    __shared__ int bs[256];
    int chunk = (N + 1023) / 1024;
    int lo = min(t * chunk, N);
    int hi = min(lo + chunk, N);
    if (t < 256) bins[t] = 0;
    __syncthreads();
    int s = 0;
    for (int i = lo; i < hi; i++) {
      int d = cnt[i];
      s += d;
      atomicAdd(&bins[min(d, 255)], 1);
    }
    part[t] = s;
    __syncthreads();
    for (int off = 1; off < 1024; off <<= 1) {
      int v = (t >= off) ? part[t - off] : 0;
      __syncthreads();
      part[t] += v;
      __syncthreads();
    }
    if (t < 256) bs[t] = bins[t];
    __syncthreads();
    for (int off = 1; off < 256; off <<= 1) {
      int v = (t < 256 && t >= off) ? bs[t - off] : 0;
      __syncthreads();
      if (t < 256) bs[t] += v;
      __syncthreads();
    }
    if (t < 256) bins[t] = (t == 0) ? 0 : bs[t - 1];
    __syncthreads();
    for (int i = lo; i < hi; i++) {
      int d = min(cnt[i], 255);
      int pos = atomicAdd(&bins[d], 1);
      perm[pos] = i;
    }
    __syncthreads();
    int run = (t == 0) ? 0 : part[t - 1];
    for (int i = lo; i < hi; i++) {
      int d = cnt[i];
      row_ptr[i] = run;
      cnt[i] = run;
      run += d;
    }
    if (t == 1023) row_ptr[N] = part[1023];
  } else {
    int col = t & 255, ro = t >> 8;
    float mu = musum[col] * invN;
    float var = sqsum[col] * invN - mu * mu;
    float sc = gamma[col] * rsqrtf(var + 1e-5f);
    float sh = beta[col] - mu * sc;
    for (int r = (blockIdx.x - 1) * 4 + ro; r < N; r += 256 * 4) {
      size_t idx = (size_t)r * 256 + col;
      xin[idx] = f2bf(x[idx] * sc + sh);
    }
  }
}

// ---------------------------------------------------------------------------
// PREP-3 (merged): CSR fill || weight prep (transposes + al-folds + zero-pads)
// ---------------------------------------------------------------------------
__global__ void prep3_kernel(const int* __restrict__ ei, int E, int N, int FILLB,
                             int* __restrict__ cursor, int* __restrict__ csr_src,
                             const float* __restrict__ W1, const float* __restrict__ a1s,
                             const float* __restrict__ a1d, const float* __restrict__ W2,
                             const float* __restrict__ a2s, const float* __restrict__ a2d,
                             const float* __restrict__ W3, const float* __restrict__ a3s,
                             const float* __restrict__ a3d, u16* __restrict__ Wt1,
                             u16* __restrict__ Wt2, u16* __restrict__ Wt3) {
  int b = blockIdx.x;
  if (b < FILLB) {
    int e = b * 256 + threadIdx.x;
    int ET = E + N;
    if (e < ET) {
      int s, d;
      if (e < E) { s = ei[e]; d = ei[E + e]; }
      else       { s = e - E; d = s; }
      int pos = atomicAdd(&cursor[d], 1);
      csr_src[pos] = s;
    }
    return;
  }
  const int S1 = 1024 * 256, S2 = 64 * 1280, S3 = 128 * 64;
  const int A1 = 32 * 256, A2 = 16 * 1280, A3 = 16 * 64;
  const int Z1 = 96 * 256, Z2 = 16 * 1280, Z3 = 16 * 64;
  int o = (b - FILLB) * 256 + threadIdx.x;
  if (o < S1) {
    int n = o / 256, k = o % 256;
    Wt1[o] = f2bf(W1[(size_t)k * 1024 + n]);
    return;
  }
  o -= S1;
  if (o < S2) {
    int n = o / 1280, k = o % 1280;
    Wt2[o] = f2bf(W2[(size_t)k * 64 + n]);
    return;
  }
  o -= S2;
  if (o < S3) {
    int n = o / 64, k = o % 64;
    Wt3[o] = f2bf(W3[(size_t)k * 128 + n]);
    return;
  }
  o -= S3;
  if (o < A1) {
    int jj = o / 256, k = o % 256, h = jj >> 1;
    const float* av = (jj & 1) ? a1d : a1s;
    float s = 0.f;
    for (int c = 0; c < 64; c++) s += W1[(size_t)k * 1024 + h * 64 + c] * av[h * 64 + c];
    Wt1[(size_t)(1024 + jj) * 256 + k] = f2bf(s);
    return;
  }
  o -= A1;
  if (o < A2) {
    int jj = o / 1280, k = o % 1280, h = jj >> 1;
    const float* av = (jj & 1) ? a2d : a2s;
    float s = 0.f;
    for (int c = 0; c < 8; c++) s += W2[(size_t)k * 64 + h * 8 + c] * av[h * 8 + c];
    Wt2[(size_t)(64 + jj) * 1280 + k] = f2bf(s);
    return;
  }
  o -= A2;
  if (o < A3) {
    int jj = o / 64, k = o % 64, h = jj >> 1;
    const float* av = (jj & 1) ? a3d : a3s;
    float s = 0.f;
    for (int c = 0; c < 16; c++) s += W3[(size_t)k * 128 + h * 16 + c] * av[h * 16 + c];
    Wt3[(size_t)(128 + jj) * 64 + k] = f2bf(s);
    return;
  }
  o -= A3;
  if (o < Z1) { Wt1[1056 * 256 + o] = 0; return; }
  o -= Z1;
  if (o < Z2) { Wt2[80 * 1280 + o] = 0; return; }
  o -= Z2;
  if (o < Z3) { Wt3[144 * 64 + o] = 0; return; }
}

// ---------------------------------------------------------------------------
// bf16 MFMA GEMM, generalized BK, double-buffered LDS via global_load_lds.
// Fused al epilogue (transposed [H][ALP] al output).
// ---------------------------------------------------------------------------
template <int BM, int BN, int FM, int FN, int BK>
__global__ __launch_bounds__(256) void mfma_gemm_al(
    const u16* __restrict__ A1, const u16* __restrict__ A2, int K1, int K,
    const u16* __restrict__ Wt, u16* __restrict__ Ch, int NcH,
    float* __restrict__ als, float* __restrict__ ald, int ALN, int ALP, int M) {
  constexpr int KC8 = BK / 8;          // 16B chunks per row of a K-tile
  constexpr int ACH = (BM * BK) / 8;
  constexpr int BCH = (BN * BK) / 8;
  static_assert(BM == 2 * FM * 16 && BN == 2 * FN * 16, "wave grid 2x2");
  __shared__ u16 As[2][BM * BK];
  __shared__ u16 Bs[2][BN * BK];
  int t = threadIdx.x;
  int m0 = blockIdx.x * BM, n0 = blockIdx.y * BN;
  int r = t & 15;
  int g = (t >> 4) & 3;
  int wid = t >> 6;
  int wm0 = (wid >> 1) * (FM * 16);
  int wn0 = (wid & 1) * (FN * 16);
  int K8 = K >> 3;
  int K2 = K - K1;

  auto stage = [&](int buf, int k0) {
    const u16* Aseg;
    int sA, kl;
    if (k0 < K1) { Aseg = A1; sA = K1; kl = k0; }
    else         { Aseg = A2; sA = K2; kl = k0 - K1; }
#pragma unroll
    for (int i = 0; i < (ACH + 255) / 256; i++) {
      int c = i * 256 + t;
      if (ACH % 256 == 0 || c < ACH) {
        int m = c / KC8, kb = c % KC8;
        __builtin_amdgcn_global_load_lds(
            (const __attribute__((address_space(1))) void*)(Aseg + (size_t)(m0 + m) * sA + kl + kb * 8),
            (__attribute__((address_space(3))) void*)(&As[buf][c * 8]), 16, 0, 0);
      }
    }
#pragma unroll
    for (int i = 0; i < (BCH + 255) / 256; i++) {
      int c = i * 256 + t;
      if (BCH % 256 == 0 || c < BCH) {
        int nn = c / KC8, kb = c % KC8;
        __builtin_amdgcn_global_load_lds(
            (const __attribute__((address_space(1))) void*)(Wt + ((size_t)(n0 + nn) * K8 + (k0 >> 3) + kb) * 8),
            (__attribute__((address_space(3))) void*)(&Bs[buf][c * 8]), 16, 0, 0);
      }
    }
  };

  f32x4 acc[FM][FN] = {};
  asm volatile("s_nop 7\n\ts_nop 7" :::);  // VALU acc-init -> MFMA SrcC hazard guard

  stage(0, 0);
  __syncthreads();  // vmcnt(0) drain + barrier: tile 0 resident
  int nt = K / BK;
  for (int ts = 0; ts < nt; ts++) {
    if (ts + 1 < nt) stage((ts + 1) & 1, (ts + 1) * BK);  // overlap with compute
    int cur = ts & 1;
#pragma unroll
    for (int ks = 0; ks < BK / 32; ks++) {
      u32x4 af[FM], bfr[FN];
#pragma unroll
      for (int fi = 0; fi < FM; fi++)
        af[fi] = *(const u32x4*)(&As[cur][((wm0 + fi * 16 + r) * KC8 + ks * 4 + g) * 8]);
#pragma unroll
      for (int fj = 0; fj < FN; fj++)
        bfr[fj] = *(const u32x4*)(&Bs[cur][((wn0 + fj * 16 + r) * KC8 + ks * 4 + g) * 8]);
#pragma unroll
      for (int fi = 0; fi < FM; fi++)
#pragma unroll
        for (int fj = 0; fj < FN; fj++) mfma16(acc[fi][fj], af[fi], bfr[fj]);
    }
    __syncthreads();  // drains vmcnt (next tile ready) + ds_reads of cur done
  }
  asm volatile("s_nop 7\n\ts_nop 7" :::);  // MFMA -> VALU read hazard guard

#pragma unroll
  for (int fi = 0; fi < FM; fi++) {
#pragma unroll
    for (int fj = 0; fj < FN; fj++) {
#pragma unroll
      for (int v = 0; v < 4; v++) {
        int m = m0 + wm0 + fi * 16 + g * 4 + v;
        int nn = n0 + wn0 + fj * 16 + r;
        if (m < M) {
          float val = acc[fi][fj][v];
          if (nn < NcH) {
            Ch[(size_t)m * NcH + nn] = f2bf(val);
          } else {
            int j = nn - NcH;
            if (j < ALN) ((j & 1) ? ald : als)[(size_t)(j >> 1) * ALP + m] = val;
          }
        }
      }
    }
  }
}

// ---------------------------------------------------------------------------
// Layer-1 aggregation: GROUP-SLICED + XCD-affine + one-pass online softmax.
// pk_fma inner loop. Wave = 8 degree-matched nodes, same head.
// ---------------------------------------------------------------------------
__global__ __launch_bounds__(256) void gat_agg1_gs(
    const u16* __restrict__ xwh, const float* __restrict__ alsrc,
    const float* __restrict__ aldst, const int* __restrict__ row_ptr,
    const int* __restrict__ csr_src, const int* __restrict__ perm,
    const float* __restrict__ bias, const float* __restrict__ slope_p,
    u16* __restrict__ out, int N, int ALP, int NBH) {
  constexpr int U = 4;
  int b = blockIdx.x;
  int xcd = b & 7, seq = b >> 3;
  int phase = seq / NBH, nb = seq - phase * NBH;
  int h = xcd + (phase << 3);
  int lane = threadIdx.x & 63;
  int g = lane >> 3, l8 = lane & 7;
  int ti = nb * 32 + (threadIdx.x >> 6) * 8 + g;
  int n = perm[min(ti, N - 1)];
  const float* alh = alsrc + (size_t)h * ALP;
  float ad = aldst[(size_t)h * ALP + n];
  int start = row_ptr[n];
  int end = row_ptr[n + 1];
  int deg = (ti < N) ? end - start : 0;
  int endm1 = end - 1;

  float m = -1e30f, s = 0.f;
  f32x2 acc2[4] = {};
  const u16* base = xwh + (size_t)h * 64 + (size_t)l8 * 8;

  auto fma8 = [&](const u32x4& v, float w) {
    f32x2 w2;
    w2.x = w;
    w2.y = w;
#pragma unroll
    for (int i = 0; i < 4; i++) pkfma(acc2[i], unpk(v[i]), w2);
  };

  int c[U];
#pragma unroll
  for (int i = 0; i < U; i++) c[i] = csr_src[min(start + i, endm1)];
  int j = 0;
  for (; j + U <= deg; j += U) {
    u32x4 v[U];
    float e[U];
#pragma unroll
    for (int i = 0; i < U; i++) v[i] = *(const u32x4*)(base + (size_t)c[i] * 1024);
#pragma unroll
    for (int i = 0; i < U; i++) e[i] = lrelu(alh[c[i]] + ad);
#pragma unroll
    for (int i = 0; i < U; i++) c[i] = csr_src[min(start + j + U + i, endm1)];
    float mn = fmaxf(fmaxf(e[0], e[1]), fmaxf(e[2], e[3]));
    if (mn > m) {
      float sc = __expf(m - mn);
      s *= sc;
#pragma unroll
      for (int k = 0; k < 4; k++) acc2[k] *= sc;
      m = mn;
    }
#pragma unroll
    for (int i = 0; i < U; i++) {
      float w = __expf(e[i] - m);
      s += w;
      fma8(v[i], w);
    }
  }
  for (int i = 0; j < deg; j++, i++) {
    u32x4 v = *(const u32x4*)(base + (size_t)c[i] * 1024);
    float e = lrelu(alh[c[i]] + ad);
    if (e > m) {
      float sc = __expf(m - e);
      s *= sc;
#pragma unroll
      for (int k = 0; k < 4; k++) acc2[k] *= sc;
      m = e;
    }
    float w = __expf(e - m);
    s += w;
    fma8(v, w);
  }
  float rr = 1.f / (s + 1e-16f);

  if (ti < N) {
    float p = slope_p[0];
    u32 ow[4];
#pragma unroll
    for (int i = 0; i < 4; i++) {
      int cc = h * 64 + l8 * 8 + 2 * i;
      float v0 = acc2[i].x * rr + bias[cc];
      float v1 = acc2[i].y * rr + bias[cc + 1];
      v0 = (v0 >= 0.f) ? v0 : p * v0;
      v1 = (v1 >= 0.f) ? v1 : p * v1;
      ow[i] = (u32)f2bf(v0) | ((u32)f2bf(v1) << 16);
    }
    *(u32x4*)(out + (size_t)n * 1024 + h * 64 + l8 * 8) = *(u32x4*)ow;
  }
}

// ---------------------------------------------------------------------------
// Layer-2 aggregation: wave = 8 degree-matched nodes, lane = 8 cols (head =
// lane&7), pk_fma inner loop, one-pass online softmax.
// ---------------------------------------------------------------------------
__global__ __launch_bounds__(256) void gat_agg2_gs(
    const u16* __restrict__ xwh, const float* __restrict__ alsrc,
    const float* __restrict__ aldst, const int* __restrict__ row_ptr,
    const int* __restrict__ csr_src, const int* __restrict__ perm,
    const float* __restrict__ bias, const float* __restrict__ slope_p,
    u16* __restrict__ out, int N, int ALP) {
  constexpr int U = 4;
  int lane = threadIdx.x & 63;
  int g = lane >> 3, l8 = lane & 7;  // l8 = col-block = head
  int ti = blockIdx.x * 32 + (threadIdx.x >> 6) * 8 + g;
  int n = perm[min(ti, N - 1)];
  const float* alh = alsrc + (size_t)l8 * ALP;
  float ad = aldst[(size_t)l8 * ALP + n];
  int start = row_ptr[n];
  int end = row_ptr[n + 1];
  int deg = (ti < N) ? end - start : 0;
  int endm1 = end - 1;

  float m = -1e30f, s = 0.f;
  f32x2 acc2[4] = {};
  const u16* base = xwh + (size_t)l8 * 8;

  auto fma8 = [&](const u32x4& v, float w) {
    f32x2 w2;
    w2.x = w;
    w2.y = w;
#pragma unroll
    for (int i = 0; i < 4; i++) pkfma(acc2[i], unpk(v[i]), w2);
  };

  int c[U];
#pragma unroll
  for (int i = 0; i < U; i++) c[i] = csr_src[min(start + i, endm1)];
  int j = 0;
  for (; j + U <= deg; j += U) {
    u32x4 v[U];
    float e[U];
#pragma unroll
    for (int i = 0; i < U; i++) v[i] = *(const u32x4*)(base + (size_t)c[i] * 64);
#pragma unroll
    for (int i = 0; i < U; i++) e[i] = lrelu(alh[c[i]] + ad);
#pragma unroll
    for (int i = 0; i < U; i++) c[i] = csr_src[min(start + j + U + i, endm1)];
    float mn = fmaxf(fmaxf(e[0], e[1]), fmaxf(e[2], e[3]));
    if (mn > m) {
      float sc = __expf(m - mn);
      s *= sc;
#pragma unroll
      for (int k = 0; k < 4; k++) acc2[k] *= sc;
      m = mn;
    }
#pragma unroll
    for (int i = 0; i < U; i++) {
      float w = __expf(e[i] - m);
      s += w;
      fma8(v[i], w);
    }
  }
  for (int i = 0; j < deg; j++, i++) {
    u32x4 v = *(const u32x4*)(base + (size_t)c[i] * 64);
    float e = lrelu(alh[c[i]] + ad);
    if (e > m) {
      float sc = __expf(m - e);
      s *= sc;
#pragma unroll
      for (int k = 0; k < 4; k++) acc2[k] *= sc;
      m = e;
    }
    float w = __expf(e - m);
    s += w;
    fma8(v, w);
  }
  float rr = 1.f / (s + 1e-16f);

  if (ti < N) {
    float p = slope_p[0];
    u32 ow[4];
#pragma unroll
    for (int i = 0; i < 4; i++) {
      int cc = l8 * 8 + 2 * i;
      float v0 = acc2[i].x * rr + bias[cc];
      float v1 = acc2[i].y * rr + bias[cc + 1];
      v0 = (v0 >= 0.f) ? v0 : p * v0;
      v1 = (v1 >= 0.f) ? v1 : p * v1;
      ow[i] = (u32)f2bf(v0) | ((u32)f2bf(v1) << 16);
    }
    *(u32x4*)(out + (size_t)n * 64 + l8 * 8) = *(u32x4*)ow;
  }
}

// ---------------------------------------------------------------------------
// Layer-3 aggregation: wave = 4 degree-matched nodes x 16 lanes, pk_fma,
// one-pass online softmax, head-mean via shfl_xor, pairwise log_softmax.
// ---------------------------------------------------------------------------
__global__ __launch_bounds__(256) void gat_agg3_gs(
    const u16* __restrict__ xwh, const float* __restrict__ alsrc,
    const float* __restrict__ aldst, const int* __restrict__ row_ptr,
    const int* __restrict__ csr_src, const int* __restrict__ perm,
    const float* __restrict__ bias, float* __restrict__ out, int N, int ALP) {
  constexpr int U = 4;
  int lane = threadIdx.x & 63;
  int g = lane >> 4, l16 = lane & 15;
  int head = l16 >> 1;
  int ti = blockIdx.x * 16 + (threadIdx.x >> 6) * 4 + g;
  int n = perm[min(ti, N - 1)];
  const float* alh = alsrc + (size_t)head * ALP;
  float ad = aldst[(size_t)head * ALP + n];
  int start = row_ptr[n];
  int end = row_ptr[n + 1];
  int deg = (ti < N) ? end - start : 0;
  int endm1 = end - 1;

  float m = -1e30f, s = 0.f;
  f32x2 acc2[4] = {};
  const u16* base = xwh + (size_t)l16 * 8;

  auto fma8 = [&](const u32x4& v, float w) {
    f32x2 w2;
    w2.x = w;
    w2.y = w;
#pragma unroll
    for (int i = 0; i < 4; i++) pkfma(acc2[i], unpk(v[i]), w2);
  };

  int c[U];
#pragma unroll
  for (int i = 0; i < U; i++) c[i] = csr_src[min(start + i, endm1)];
  int j = 0;
  for (; j + U <= deg; j += U) {
    u32x4 v[U];
    float e[U];
#pragma unroll
    for (int i = 0; i < U; i++) v[i] = *(const u32x4*)(base + (size_t)c[i] * 128);
#pragma unroll
    for (int i = 0; i < U; i++) e[i] = lrelu(alh[c[i]] + ad);
#pragma unroll
    for (int i = 0; i < U; i++) c[i] = csr_src[min(start + j + U + i, endm1)];
    float mn = fmaxf(fmaxf(e[0], e[1]), fmaxf(e[2], e[3]));
    if (mn > m) {
      float sc = __expf(m - mn);
      s *= sc;
#pragma unroll
      for (int k = 0; k < 4; k++) acc2[k] *= sc;
      m = mn;
    }
#pragma unroll
    for (int i = 0; i < U; i++) {
      float w = __expf(e[i] - m);
      s += w;
      fma8(v[i], w);
    }
  }
  for (int i = 0; j < deg; j++, i++) {
    u32x4 v = *(const u32x4*)(base + (size_t)c[i] * 128);
    float e = lrelu(alh[c[i]] + ad);
    if (e > m) {
      float sc = __expf(m - e);
      s *= sc;
#pragma unroll
      for (int k = 0; k < 4; k++) acc2[k] *= sc;
      m = e;
    }
    float w = __expf(e - m);
    s += w;
    fma8(v, w);
  }
  float rr = 1.f / (s + 1e-16f);

  float a8[8];
#pragma unroll
  for (int k = 0; k < 4; k++) {
    a8[2 * k] = acc2[k].x * rr;
    a8[2 * k + 1] = acc2[k].y * rr;
  }

  // sum over heads: lanes differing in bits 1..3 of l16 hold other heads
#pragma unroll
  for (int st = 2; st <= 8; st <<= 1)
#pragma unroll
    for (int k = 0; k < 8; k++) a8[k] += __shfl_xor(a8[k], st);

  int half = l16 & 1;  // which 8 of the 16 output cols this lane holds
  float v8[8];
  float mx = -1e30f;
#pragma unroll
  for (int k = 0; k < 8; k++) {
    v8[k] = a8[k] * 0.125f + bias[half * 8 + k];
    mx = fmaxf(mx, v8[k]);
  }
  mx = fmaxf(mx, __shfl_xor(mx, 1));
  float se = 0.f;
#pragma unroll
  for (int k = 0; k < 8; k++) se += __expf(v8[k] - mx);
  se += __shfl_xor(se, 1);
  float lse = mx + logf(se);
  if (ti < N && l16 < 2) {
    float4 o0 = make_float4(v8[0] - lse, v8[1] - lse, v8[2] - lse, v8[3] - lse);
    float4 o1 = make_float4(v8[4] - lse, v8[5] - lse, v8[6] - lse, v8[7] - lse);
    float* op = out + (size_t)n * 16 + half * 8;
    *(float4*)op = o0;
    *(float4*)(op + 4) = o1;
  }
}

// ---------------------------------------------------------------------------
extern "C" void kernel_launch(void* const* d_in, const int* in_sizes, int n_in,
                              void* d_out, int out_size, void* d_ws, size_t ws_size,
                              hipStream_t stream) {
  const float* x        = (const float*)d_in[0];
  const int*   ei       = (const int*)d_in[1];
  const float* bn_gamma = (const float*)d_in[2];
  const float* bn_beta  = (const float*)d_in[3];
  const float* W1       = (const float*)d_in[4];
  const float* a1s      = (const float*)d_in[5];
  const float* a1d      = (const float*)d_in[6];
  const float* b1       = (const float*)d_in[7];
  const float* p1       = (const float*)d_in[8];
  const float* W2       = (const float*)d_in[9];
  const float* a2s      = (const float*)d_in[10];
  const float* a2d      = (const float*)d_in[11];
  const float* b2       = (const float*)d_in[12];
  const float* p2       = (const float*)d_in[13];
  const float* W3       = (const float*)d_in[14];
  const float* a3s      = (const float*)d_in[15];
  const float* a3d      = (const float*)d_in[16];
  const float* b3       = (const float*)d_in[17];
  float* out = (float*)d_out;

  const int F  = in_sizes[2];       // 256
  const int N  = in_sizes[0] / F;   // 20000
  const int E  = in_sizes[1] / 2;   // 320000
  const int ET = E + N;
  const int MP = ((N + 127) / 128) * 128;  // MFMA row padding (also al stride)

  size_t off = 0;
  auto alloc = [&](size_t bytes) -> char* {
    char* r = (char*)d_ws + off;
    off += (bytes + 255) & ~(size_t)255;
    return r;
  };
  float* musum   = (float*)alloc(F * 4);
  float* sqsum   = (float*)alloc(F * 4);
  int*   cursor  = (int*)alloc((size_t)N * 4);
  int*   row_ptr = (int*)alloc((size_t)(N + 1) * 4);
  int*   csr_src = (int*)alloc((size_t)ET * 4);
  int*   perm    = (int*)alloc((size_t)N * 4);
  float* al_s    = (float*)alloc((size_t)16 * MP * 4);
  float* al_d    = (float*)alloc((size_t)16 * MP * 4);
  u16*   Wt1     = (u16*)alloc((size_t)1152 * 256 * 2);
  u16*   Wt2     = (u16*)alloc((size_t)96 * 1280 * 2);
  u16*   Wt3     = (u16*)alloc((size_t)160 * 64 * 2);
  u16*   x_in_h  = (u16*)alloc((size_t)MP * 256 * 2);
  u16*   xw1h    = (u16*)alloc((size_t)MP * 1024 * 2);
  u16*   h1      = (u16*)alloc((size_t)MP * 1024 * 2);
  u16*   xw2h    = (u16*)alloc((size_t)MP * 64 * 2);
  u16*   h2h     = (u16*)alloc((size_t)MP * 64 * 2);
  u16*   xw3h    = (u16*)alloc((size_t)MP * 128 * 2);

  // ---- single memset: musum + sqsum + cursor ----
  hipMemsetAsync(musum, 0, (size_t)2 * F * 4 + (size_t)N * 4, stream);

  // ---- PREP-1: BN stats || CSR count ----
  int CNTB = (ET + 255) / 256;
  prep1_kernel<<<256 + CNTB, 256, 0, stream>>>(x, musum, sqsum, ei, E, N, cursor);

  // ---- PREP-2: scan+perm (block 0) || BN apply (blocks 1..256) ----
  prep2_kernel<<<257, 1024, 0, stream>>>(cursor, row_ptr, perm, x, musum, sqsum, bn_gamma,
                                         bn_beta, x_in_h, N, 1.0f / (float)N);

  // ---- PREP-3: CSR fill || weight prep ----
  {
    int total_wt = 1024 * 256 + 64 * 1280 + 128 * 64
                 + 32 * 256 + 16 * 1280 + 16 * 64
                 + 96 * 256 + 16 * 1280 + 16 * 64;
    int WTB = (total_wt + 255) / 256;
    prep3_kernel<<<CNTB + WTB, 256, 0, stream>>>(ei, E, N, CNTB, cursor, csr_src, W1, a1s, a1d,
                                                 W2, a2s, a2d, W3, a3s, a3d, Wt1, Wt2, Wt3);
  }

  // ---- Layer 1: [N,256]@[256,1024(+32al)] MFMA, H=16, C=64 ----
  {
    dim3 grid(MP / 128, 9);  // 9th tile covers al cols 1024..1151
    mfma_gemm_al<128, 128, 4, 4, 32><<<grid, 256, 0, stream>>>(
        x_in_h, x_in_h, 256, 256, Wt1, xw1h, 1024, al_s, al_d, 32, MP, N);
    int NBH = (N + 31) / 32;
    gat_agg1_gs<<<8 * NBH * 2, 256, 0, stream>>>(xw1h, al_s, al_d, row_ptr, csr_src, perm, b1, p1,
                                                 h1, N, MP, NBH);
  }

  // ---- Layer 2: concat([x_in,h1]) [N,1280]@[1280,64+16al] MFMA, H=8, C=8 ----
  // BM=32 (626 blocks, 2.4/CU) + BK=64 (20 K-steps) for parallelism.
  {
    dim3 grid((N + 31) / 32, 1);
    mfma_gemm_al<32, 96, 1, 3, 64><<<grid, 256, 0, stream>>>(
        x_in_h, h1, 256, 1280, Wt2, xw2h, 64, al_s, al_d, 16, MP, N);
    gat_agg2_gs<<<(N + 31) / 32, 256, 0, stream>>>(xw2h, al_s, al_d, row_ptr, csr_src, perm, b2,
                                                   p2, h2h, N, MP);
  }

  // ---- Layer 3: [N,64]@[64,128+16al] MFMA, H=8, C=16 (single K-step) ----
  {
    dim3 grid((N + 63) / 64, 1);
    mfma_gemm_al<64, 160, 2, 5, 64><<<grid, 256, 0, stream>>>(
        h2h, h2h, 64, 64, Wt3, xw3h, 128, al_s, al_d, 16, MP, N);
    gat_agg3_gs<<<(N + 15) / 16, 256, 0, stream>>>(xw3h, al_s, al_d, row_ptr, csr_src, perm, b3,
                                                   out, N, MP);
  }
}